// Round 11
// baseline (339.189 us; speedup 1.0000x reference)
//
#include <hip/hip_runtime.h>
#include <hip/hip_fp16.h>
#include <stdint.h>

// GCN forward. N=100000, E=3000000, G=256, F_IN=64, NHID=32.
// R1: 96M global scatter-atomics = L2 atomic ceiling (312us) -> gather.
// R2: naive CSR build = 16x write amplification across 8 incoherent L2s
//     (write-allocate thrash on random 4B stores).
// R3/R7/R8: 8-slice XCD build (one XCD owns each region) = clean writes;
//     fewer slices = multiple XCDs/region = ping-pong thrash returns.
// R5: LDS float atomics 3.6cyc/op = poison at 96M ops.
// R6: small hot global atomic arrays = 32B HBM ping-pong per op.
// R9: nontemporal_store is WRITE-THROUGH on gfx950: random sub-line nt
//     stores cost ~56B HBM each. nt only for full-line streaming.
// R10: fused pipeline, 7 dispatches, 302us. ewc byte-scatter exposed:
//     3M random byte stores = 119MB WRITE (40B/store) - same pathology.
// R11: ewc scatter XCD-sliced too (slice=blockIdx%8 owns E/8 edge range,
//     375KB L2-resident region/XCD; masks re-read 8x via L3).

#define BLK 256
#define NCHUNK 512          // edge chunks for count/scatter
#define MAXNB 1600          // max buckets (N<=102400)
#define ENTCAP 2560         // per-bucket LDS entries (lambda=1920, 14 sigma)

// kA1: fused. Blocks [0,NCHUNK): per-chunk bucket histogram (LDS).
// Blocks [NCHUNK, NCHUNK+256): XCD-sliced edge-class scatter: slice s
// (blockIdx%8 -> one XCD) writes only ewc[e] for e in its E/8 range.
__global__ void kA1(const int* __restrict__ col, int* __restrict__ cnt,
                    int n_edges, int NB,
                    const int* __restrict__ km, const int* __restrict__ um,
                    const int* __restrict__ om, int s0, int s1, int s2,
                    uint8_t* __restrict__ ewc) {
    __shared__ int lh[MAXNB];
    int t = threadIdx.x;
    if (blockIdx.x < NCHUNK) {
        int c = blockIdx.x;
        for (int b = t; b < NB; b += BLK) lh[b] = 0;
        __syncthreads();
        int chunk = (n_edges + NCHUNK - 1) / NCHUNK;
        int e0 = c * chunk, e1 = min(e0 + chunk, n_edges);
        for (int e = e0 + t; e < e1; e += BLK) atomicAdd(&lh[col[e] >> 6], 1);
        __syncthreads();
        for (int b = t; b < NB; b += BLK) cnt[(size_t)c * NB + b] = lh[b];
    } else {
        int m = blockIdx.x - NCHUNK;        // 0..255
        int sl = m & 7, g = m >> 3;         // 8 slices x 32 chunks
        int per = (n_edges + 7) >> 3;       // slice width in edge-id space
        int elo = sl * per, ehi = min(elo + per, n_edges);
        int total = s0 + s1 + s2;
        int chunk = (total + 31) / 32;
        int i0 = g * chunk, i1 = min(i0 + chunk, total);
        for (int i = i0 + t; i < i1; i += BLK) {
            int e; uint8_t cls;
            if (i < s0)           { e = km[i];           cls = 0; }
            else if (i < s0 + s1) { e = um[i - s0];      cls = 1; }
            else                  { e = om[i - s0 - s1]; cls = 2; }
            if (e >= elo && e < ehi) ewc[e] = cls;
        }
    }
}

// kB2: 16 buckets per block. Tile cnt[c][b0..b0+15] through LDS with
// coalesced 64B reads, scan over c, write offTT TRANSPOSED so kC reads
// its cursor row sequentially.
__global__ void kB2(const int* __restrict__ cnt, int* __restrict__ offTT,
                    int* __restrict__ tot, int NB) {
    __shared__ int tile[NCHUNK * 16];     // 32KB
    __shared__ int segs[16][17];
    int t = threadIdx.x;
    int b0 = blockIdx.x * 16;
    for (int idx = t; idx < NCHUNK * 16; idx += BLK) {
        int c = idx >> 4, b = idx & 15;
        tile[idx] = (b0 + b < NB) ? cnt[(size_t)c * NB + b0 + b] : 0;
    }
    __syncthreads();
    int b = t & 15, seg = t >> 4;         // 16 segs x 16 buckets
    int psum = 0;
#pragma unroll
    for (int k = 0; k < 32; ++k) psum += tile[(seg * 32 + k) * 16 + b];
    segs[seg][b] = psum;
    __syncthreads();
    int ex = 0;
    for (int ss = 0; ss < seg; ++ss) ex += segs[ss][b];
    int run = ex;
#pragma unroll
    for (int k = 0; k < 32; ++k) {
        int c = seg * 32 + k;
        if (b0 + b < NB) offTT[(size_t)c * NB + b0 + b] = run;
        run += tile[c * 16 + b];
    }
    if (seg == 15 && b0 + b < NB) tot[b0 + b] = run;
}

// kBase3: fused. Blocks 0..7: fold emb through gcn (Wfull, hWbias).
// Block 8: exclusive scan of tot[NB] -> base_[0..NB].
__global__ void kBase3(const int* __restrict__ tot, int* __restrict__ base_, int NB,
                       const float* __restrict__ emb_W, const float* __restrict__ emb_b,
                       const float* __restrict__ gcn_W,
                       float* __restrict__ Wfull, float* __restrict__ hWbias) {
    int t = threadIdx.x;
    if (blockIdx.x < 8) {
        int k = blockIdx.x * 8 + (t >> 5), j = t & 31;
        float acc;
        if (k == 0) {
            acc = gcn_W[j];
        } else {
            int m = k - 1;
            acc = 0.0f;
#pragma unroll 9
            for (int tt = 0; tt < 63; ++tt)
                acc += emb_W[m * 63 + tt] * gcn_W[(1 + tt) * 32 + j];
        }
        Wfull[k * 32 + j] = acc;
        if (blockIdx.x == 0 && t < 32) {
            float bacc = 0.0f;
            for (int tt = 0; tt < 63; ++tt)
                bacc += emb_b[tt] * gcn_W[(1 + tt) * 32 + t];
            hWbias[t] = bacc;
        }
    } else {
        __shared__ int s[BLK];
        const int K = 7;  // 256*7 = 1792 >= MAXNB
        int v[K]; int sum = 0;
#pragma unroll
        for (int k = 0; k < K; ++k) {
            int i = t * K + k;
            v[k] = (i < NB) ? tot[i] : 0;
            sum += v[k];
        }
        s[t] = sum; __syncthreads();
        for (int st = 1; st < BLK; st <<= 1) {
            int x = (t >= st) ? s[t - st] : 0;
            __syncthreads(); s[t] += x; __syncthreads();
        }
        int ex = (t == 0) ? 0 : s[t - 1];
#pragma unroll
        for (int k = 0; k < K; ++k) {
            int i = t * K + k;
            if (i < NB) base_[i] = ex;
            ex += v[k];
        }
        if (t == BLK - 1) base_[NB] = s[BLK - 1];
    }
}

// kC: 8-slice XCD-partitioned scatter (R8-proven). slice = blockIdx&7 ->
// exactly ONE XCD owns each csrB region (~1.5MB, L2-resident).
// Entry = (local_col<<19)|(row<<2)|cls.
__global__ void kC_scatter(const int* __restrict__ row, const int* __restrict__ col,
                           const uint8_t* __restrict__ ewc, const int* __restrict__ base_,
                           const int* __restrict__ offTT, int* __restrict__ csrB,
                           int n_edges, int NB, int nbs) {
    __shared__ int cur[200];
    int sl = blockIdx.x & 7, c = blockIdx.x >> 3, t = threadIdx.x;
    int b0 = sl * nbs, b1 = min(b0 + nbs, NB);
    const int* offrow = offTT + (size_t)c * NB;
    for (int b = b0 + t; b < b1; b += BLK)
        cur[b - b0] = base_[b] + offrow[b];
    __syncthreads();
    int chunk = (n_edges + NCHUNK - 1) / NCHUNK;
    int e0 = c * chunk, e1 = min(e0 + chunk, n_edges);
    for (int e = e0 + t; e < e1; e += BLK) {
        int cc = col[e]; int b = cc >> 6;
        if (b >= b0 && b < b1) {
            int pos = atomicAdd(&cur[b - b0], 1);
            csrB[pos] = ((cc & 63) << 19) | (row[e] << 2) | (ewc[e] & 3);
        }
    }
}

// k4f: fused degree + GEMM per 64-node bucket.
__global__ void k4f_gemm(const float* __restrict__ x, const float* __restrict__ Wfull,
                         const float* __restrict__ hWbias, const int* __restrict__ base_,
                         const int* __restrict__ csrB, const float* __restrict__ mw,
                         __half* __restrict__ hWs, int n_nodes) {
    __shared__ float Wl[64 * 32];      // 8KB
    __shared__ float xs[64 * 64];      // 16KB
    __shared__ int ct4[256];           // 1KB
    __shared__ float dv[64];
    int b = blockIdx.x, t = threadIdx.x;
    for (int idx = t; idx < 2048; idx += BLK) Wl[idx] = Wfull[idx];
    if (t < 256) ct4[t] = 0;
    int rowBase = b * 64;
    for (int idx = t; idx < 4096; idx += BLK) {
        int r = rowBase + (idx >> 6);
        xs[idx] = (r < n_nodes) ? x[(size_t)r * 64 + (idx & 63)] : 0.0f;
    }
    __syncthreads();
    int p0 = base_[b], p1 = base_[b + 1];
    for (int p = p0 + t; p < p1; p += BLK) {
        int e = csrB[p];
        atomicAdd(&ct4[((e >> 19) << 2) | (e & 3)], 1);
    }
    __syncthreads();
    if (t < 64) {
        float a = mw[0], bb = mw[1], c3 = mw[2];
        float m = fmaxf(a, fmaxf(bb, c3));
        float ea = __expf(a - m), eb = __expf(bb - m), ec = __expf(c3 - m);
        float inv = 1.0f / (ea + eb + ec);
        float deg = (ea * inv) * (float)ct4[t * 4]
                  + (eb * inv) * (float)ct4[t * 4 + 1]
                  + (ec * inv) * (float)ct4[t * 4 + 2]
                  + (float)ct4[t * 4 + 3]
                  + 1.0f;
        dv[t] = rsqrtf(deg);
    }
    __syncthreads();
    int j = t & 31, lr = t >> 5;
#pragma unroll
    for (int k8 = 0; k8 < 8; ++k8) {
        int r = lr + 8 * k8;
        int n = rowBase + r;
        if (n < n_nodes) {
            float acc = hWbias[j];
#pragma unroll
            for (int k = 0; k < 64; ++k)
                acc += xs[r * 64 + k] * Wl[k * 32 + j];
            hWs[(size_t)n * 32 + j] = __float2half(dv[r] * acc);
        }
    }
}

// kD: per-bucket consumer. Counting-sort edges into LDS per-node lists,
// per-node register gather (16 lanes/node, half2, 8 loads in flight),
// relu, run-length pool.
__global__ void kD_gather(const int* __restrict__ base_, const int* __restrict__ csrB,
                          const __half2* __restrict__ hws2,
                          const float* __restrict__ mw, const float* __restrict__ gcn_b,
                          const int* __restrict__ batch, float* __restrict__ pooled,
                          int n_nodes) {
    __shared__ int ent[ENTCAP];
    __shared__ float res[64 * 33];
    __shared__ int ct4[256];
    __shared__ int ct[64], st[64], cur[64];
    __shared__ float dl[64], gb[32];
    __shared__ int bl[64];
    int b = blockIdx.x, t = threadIdx.x;
    if (t < 256) ct4[t] = 0;
    if (t < 64) {
        int n = b * 64 + t;
        bl[t] = (n < n_nodes) ? batch[n] : -1;
    }
    if (t < 32) gb[t] = gcn_b[t];
    __syncthreads();
    int p0 = base_[b], p1 = base_[b + 1];
    int m = min(p1 - p0, ENTCAP);     // clamp (14 sigma margin, never hit)
    int p1c = p0 + m;
    for (int p = p0 + t; p < p1c; p += BLK) {
        int e = csrB[p];
        atomicAdd(&ct4[((e >> 19) << 2) | (e & 3)], 1);
    }
    __syncthreads();
    float a = mw[0], bb = mw[1], c3 = mw[2];
    float mx = fmaxf(a, fmaxf(bb, c3));
    float ea = __expf(a - mx), eb = __expf(bb - mx), ec = __expf(c3 - mx);
    float inv = 1.0f / (ea + eb + ec);
    float w0 = ea * inv, w1 = eb * inv, w2 = ec * inv;
    if (t < 64) {
        int c0 = ct4[t * 4], c1 = ct4[t * 4 + 1], c2 = ct4[t * 4 + 2], c33 = ct4[t * 4 + 3];
        ct[t] = c0 + c1 + c2 + c33;
        dl[t] = rsqrtf(w0 * (float)c0 + w1 * (float)c1 + w2 * (float)c2
                       + (float)c33 + 1.0f);
    }
    __syncthreads();
    if (t < 64) st[t] = ct[t];
    __syncthreads();
    for (int off = 1; off < 64; off <<= 1) {
        int v = (t < 64 && t >= off) ? st[t - off] : 0;
        __syncthreads();
        if (t < 64) st[t] += v;
        __syncthreads();
    }
    if (t < 64) { st[t] -= ct[t]; cur[t] = st[t]; }
    __syncthreads();
    for (int p = p0 + t; p < p1c; p += BLK) {
        int e = csrB[p];
        int pos = atomicAdd(&cur[e >> 19], 1);
        ent[pos] = e;
    }
    __syncthreads();
    int grp = t >> 4, j2 = t & 15;
#pragma unroll
    for (int idx = 0; idx < 4; ++idx) {
        int lc = grp + 16 * idx;
        int n = b * 64 + lc;
        float rx = 0.0f, ry = 0.0f;
        if (n < n_nodes) {
            int s = st[lc], end = s + ct[lc];
            float ax = 0.0f, ay = 0.0f;
            int p = s;
            for (; p + 8 <= end; p += 8) {
                int e0 = ent[p],     e1 = ent[p + 1], e2 = ent[p + 2], e3 = ent[p + 3];
                int e4 = ent[p + 4], e5 = ent[p + 5], e6 = ent[p + 6], e7 = ent[p + 7];
                __half2 h0 = hws2[(size_t)((e0 >> 2) & 0x1FFFF) * 16 + j2];
                __half2 h1 = hws2[(size_t)((e1 >> 2) & 0x1FFFF) * 16 + j2];
                __half2 h2 = hws2[(size_t)((e2 >> 2) & 0x1FFFF) * 16 + j2];
                __half2 h3 = hws2[(size_t)((e3 >> 2) & 0x1FFFF) * 16 + j2];
                __half2 h4 = hws2[(size_t)((e4 >> 2) & 0x1FFFF) * 16 + j2];
                __half2 h5 = hws2[(size_t)((e5 >> 2) & 0x1FFFF) * 16 + j2];
                __half2 h6 = hws2[(size_t)((e6 >> 2) & 0x1FFFF) * 16 + j2];
                __half2 h7 = hws2[(size_t)((e7 >> 2) & 0x1FFFF) * 16 + j2];
                float f0 = ((e0 & 3) == 0) ? w0 : (((e0 & 3) == 1) ? w1 : w2);
                float f1 = ((e1 & 3) == 0) ? w0 : (((e1 & 3) == 1) ? w1 : w2);
                float f2 = ((e2 & 3) == 0) ? w0 : (((e2 & 3) == 1) ? w1 : w2);
                float f3 = ((e3 & 3) == 0) ? w0 : (((e3 & 3) == 1) ? w1 : w2);
                float f4 = ((e4 & 3) == 0) ? w0 : (((e4 & 3) == 1) ? w1 : w2);
                float f5 = ((e5 & 3) == 0) ? w0 : (((e5 & 3) == 1) ? w1 : w2);
                float f6 = ((e6 & 3) == 0) ? w0 : (((e6 & 3) == 1) ? w1 : w2);
                float f7 = ((e7 & 3) == 0) ? w0 : (((e7 & 3) == 1) ? w1 : w2);
                float2 g0 = __half22float2(h0), g1 = __half22float2(h1);
                float2 g2 = __half22float2(h2), g3 = __half22float2(h3);
                float2 g4 = __half22float2(h4), g5 = __half22float2(h5);
                float2 g6 = __half22float2(h6), g7 = __half22float2(h7);
                ax += f0 * g0.x + f1 * g1.x + f2 * g2.x + f3 * g3.x
                    + f4 * g4.x + f5 * g5.x + f6 * g6.x + f7 * g7.x;
                ay += f0 * g0.y + f1 * g1.y + f2 * g2.y + f3 * g3.y
                    + f4 * g4.y + f5 * g5.y + f6 * g6.y + f7 * g7.y;
            }
            for (; p < end; ++p) {
                int e0 = ent[p];
                __half2 h0 = hws2[(size_t)((e0 >> 2) & 0x1FFFF) * 16 + j2];
                float f0 = ((e0 & 3) == 0) ? w0 : (((e0 & 3) == 1) ? w1 : w2);
                float2 g0 = __half22float2(h0);
                ax += f0 * g0.x; ay += f0 * g0.y;
            }
            float2 self = __half22float2(hws2[(size_t)n * 16 + j2]);
            float di = dl[lc];
            rx = fmaxf(di * (ax + self.x) + gb[2 * j2], 0.0f);
            ry = fmaxf(di * (ay + self.y) + gb[2 * j2 + 1], 0.0f);
        }
        res[lc * 33 + 2 * j2]     = rx;
        res[lc * 33 + 2 * j2 + 1] = ry;
    }
    __syncthreads();
    if (t < 32) {
        int j = t;
        float sum = 0.0f; int g0 = bl[0];
        for (int lc = 0; lc < 64; ++lc) {
            if (bl[lc] < 0) break;
            float val = res[lc * 33 + j];
            if (bl[lc] != g0) { atomicAdd(&pooled[g0 * 32 + j], sum); sum = 0.0f; g0 = bl[lc]; }
            sum += val;
        }
        if (g0 >= 0) atomicAdd(&pooled[g0 * 32 + j], sum);
    }
}

// k7: head: z = relu(pooled @ fc1_W + fc1_b); out = z @ out_W + out_b
__global__ void k7_head(const float* __restrict__ pooled, const float* __restrict__ fc1_W,
                        const float* __restrict__ fc1_b, const float* __restrict__ out_W,
                        const float* __restrict__ out_b, float* __restrict__ out,
                        int n_graphs) {
    __shared__ float Wl[32 * 32];
    __shared__ float bl[32];
    __shared__ float owl[32];
    int t = threadIdx.x;
    for (int idx = t; idx < 1024; idx += BLK) Wl[idx] = fc1_W[idx];
    if (t < 32) { bl[t] = fc1_b[t]; owl[t] = out_W[t]; }
    __syncthreads();
    if (t < n_graphs) {
        float p[32];
#pragma unroll
        for (int k = 0; k < 32; ++k) p[k] = pooled[t * 32 + k];
        float acc = 0.0f;
        for (int j = 0; j < 32; ++j) {
            float z = bl[j];
#pragma unroll
            for (int k = 0; k < 32; ++k) z += p[k] * Wl[k * 32 + j];
            z = fmaxf(z, 0.0f);
            acc += z * owl[j];
        }
        out[t] = acc + out_b[0];
    }
}

static inline size_t align_up(size_t v, size_t a) { return (v + a - 1) & ~(a - 1); }

extern "C" void kernel_launch(void* const* d_in, const int* in_sizes, int n_in,
                              void* d_out, int out_size, void* d_ws, size_t ws_size,
                              hipStream_t stream) {
    const float* x     = (const float*)d_in[0];
    const int*   ei    = (const int*)d_in[1];
    const int*   batch = (const int*)d_in[2];
    const int*   km    = (const int*)d_in[3];
    const int*   um    = (const int*)d_in[4];
    const int*   om    = (const int*)d_in[5];
    const float* mw    = (const float*)d_in[6];
    const float* emb_W = (const float*)d_in[7];
    const float* emb_b = (const float*)d_in[8];
    const float* gcn_W = (const float*)d_in[9];
    const float* gcn_b = (const float*)d_in[10];
    const float* fc1_W = (const float*)d_in[11];
    const float* fc1_b = (const float*)d_in[12];
    const float* out_W = (const float*)d_in[13];
    const float* out_b = (const float*)d_in[14];

    const int n_nodes  = in_sizes[0] / 64;
    const int n_edges  = in_sizes[1] / 2;
    const int s0 = in_sizes[3], s1 = in_sizes[4], s2 = in_sizes[5];
    const int n_graphs = out_size;  // 256

    const int* row = ei;
    const int* col = ei + n_edges;

    const int NB  = (n_nodes + 63) >> 6;   // 1563 buckets of 64 nodes
    const int NGB = (NB + 15) / 16;        // kB2 blocks
    const int nbs = (NB + 7) / 8;          // buckets per slice (8 slices)

    // ---- workspace layout (~28.3 MB) ----
    char* base = (char*)d_ws;
    float*   pooled = (float*)base;   base += (size_t)n_graphs * 32 * 4;   // zeroed
    int*     cnt    = (int*)base;     base += (size_t)NCHUNK * NB * 4;     // 3.2 MB
    int*     offTT  = (int*)base;     base += (size_t)NCHUNK * NB * 4;     // 3.2 MB
    int*     tot    = (int*)base;     base += (size_t)NB * 4;
    int*     base_  = (int*)base;     base += (size_t)(NB + 1) * 4;
    float*   Wfull  = (float*)base;   base += 2048 * 4;
    float*   hWbias = (float*)base;   base += 32 * 4;
    uint8_t* ewc    = (uint8_t*)base; base += align_up((size_t)n_edges, 64);
    int*     csrB   = (int*)base;     base += (size_t)n_edges * 4;         // 12 MB
    base = (char*)align_up((size_t)base, 64);
    __half*  hWs    = (__half*)base;  base += (size_t)n_nodes * 32 * 2;    // 6.4 MB

    hipMemsetAsync(pooled, 0, (size_t)n_graphs * 32 * 4, stream);

    kA1<<<NCHUNK + 256, BLK, 0, stream>>>(col, cnt, n_edges, NB,
                                          km, um, om, s0, s1, s2, ewc);
    kB2<<<NGB, BLK, 0, stream>>>(cnt, offTT, tot, NB);
    kBase3<<<9, BLK, 0, stream>>>(tot, base_, NB, emb_W, emb_b, gcn_W, Wfull, hWbias);
    kC_scatter<<<NCHUNK * 8, BLK, 0, stream>>>(row, col, ewc, base_, offTT, csrB,
                                               n_edges, NB, nbs);
    k4f_gemm<<<NB, BLK, 0, stream>>>(x, Wfull, hWbias, base_, csrB, mw, hWs, n_nodes);
    kD_gather<<<NB, BLK, 0, stream>>>(base_, csrB, (const __half2*)hWs, mw,
                                      gcn_b, batch, pooled, n_nodes);
    k7_head<<<1, BLK, 0, stream>>>(pooled, fc1_W, fc1_b, out_W, out_b, (float*)d_out, n_graphs);
}

// Round 12
// 318.569 us; speedup vs baseline: 1.0647x; 1.0647x over previous
//
#include <hip/hip_runtime.h>
#include <hip/hip_fp16.h>
#include <stdint.h>

// GCN forward. N=100000, E=3000000, G=256, F_IN=64, NHID=32.
// R1: 96M global scatter-atomics = L2 atomic ceiling (312us) -> gather.
// R2: naive CSR build = 16x write amplification (random sub-line stores,
//     8 incoherent L2s, write-allocate thrash).
// R3/R7/R8: 8-slice XCD build (one XCD owns each region) = clean writes.
// R5: LDS float atomics 3.6cyc/op = poison at 96M ops.
// R6: small hot global atomic arrays = 32B line ping-pong per op.
// R9: nontemporal_store is write-through: ~56B per random sub-line store.
// R11: slicing the ewc scatter fixed WRITE (119->6MB) but 8x mask re-read
//     cost more than it saved (FETCH 12->53MB, latency-bound). Random
//     sub-line stores are fire-and-forget; re-READS stall.
// R12: two-phase mask inversion: phase1 radix-buckets masks by edge-range
//     into dense full-line runs (exact E/8 buckets, permutation); phase2
//     per-XCD slice writes its private 375KB ewc region. No 8x re-read,
//     no write amplification. mbuf aliases csrB.

#define BLK 256
#define NCHUNK 512          // edge chunks for count/scatter
#define MAXNB 1600          // max buckets (N<=102400)
#define ENTCAP 2560         // per-bucket LDS entries (lambda=1920, 14 sigma)

// kA1: fused. Blocks [0,NCHUNK): per-chunk node-bucket histogram (LDS).
// Blocks [NCHUNK, NCHUNK+256): mask phase-1: radix masks into 8 edge-range
// buckets, packed (e<<2)|cls, dense runs via 8 global cursor atomics/block.
__global__ void kA1(const int* __restrict__ col, int* __restrict__ cnt,
                    int n_edges, int NB,
                    const int* __restrict__ km, const int* __restrict__ um,
                    const int* __restrict__ om, int s0, int s1, int s2,
                    int* __restrict__ gcur, int* __restrict__ mbuf, int per) {
    int t = threadIdx.x;
    if (blockIdx.x < NCHUNK) {
        __shared__ int lh[MAXNB];
        int c = blockIdx.x;
        for (int b = t; b < NB; b += BLK) lh[b] = 0;
        __syncthreads();
        int chunk = (n_edges + NCHUNK - 1) / NCHUNK;
        int e0 = c * chunk, e1 = min(e0 + chunk, n_edges);
        for (int e = e0 + t; e < e1; e += BLK) atomicAdd(&lh[col[e] >> 6], 1);
        __syncthreads();
        for (int b = t; b < NB; b += BLK) cnt[(size_t)c * NB + b] = lh[b];
    } else {
        __shared__ int bcnt[8], bbase[8];
        int m = blockIdx.x - NCHUNK;        // 0..255
        int total = s0 + s1 + s2;
        int chunk = (total + 255) / 256;
        int i0 = m * chunk, i1 = min(i0 + chunk, total);
        if (t < 8) bcnt[t] = 0;
        __syncthreads();
        // pass A: count per edge-range bucket
        for (int i = i0 + t; i < i1; i += BLK) {
            int e;
            if (i < s0)           e = km[i];
            else if (i < s0 + s1) e = um[i - s0];
            else                  e = om[i - s0 - s1];
            atomicAdd(&bcnt[min(e / per, 7)], 1);
        }
        __syncthreads();
        if (t < 8) {
            bbase[t] = atomicAdd(&gcur[t], bcnt[t]);
            bcnt[t] = 0;                    // reuse as local cursor
        }
        __syncthreads();
        // pass B: place packed entries into dense per-bucket runs
        for (int i = i0 + t; i < i1; i += BLK) {
            int e, cls;
            if (i < s0)           { e = km[i];           cls = 0; }
            else if (i < s0 + s1) { e = um[i - s0];      cls = 1; }
            else                  { e = om[i - s0 - s1]; cls = 2; }
            int b = min(e / per, 7);
            int pos = bbase[b] + atomicAdd(&bcnt[b], 1);
            mbuf[(size_t)b * per + pos] = (e << 2) | cls;
        }
    }
}

// kE: mask phase-2. slice sl = blockIdx&7 (one XCD) reads bucket sl
// sequentially, writes cls bytes into its PRIVATE 375KB ewc region
// (L2-resident, lines fill before writeback).
__global__ void kE_ewc(const int* __restrict__ gcur, const int* __restrict__ mbuf,
                       uint8_t* __restrict__ ewc, int per) {
    int sl = blockIdx.x & 7, k = blockIdx.x >> 3, t = threadIdx.x;
    int cnt = gcur[sl];
    int chunk = (cnt + 31) / 32;
    int i0 = k * chunk, i1 = min(i0 + chunk, cnt);
    const int* src = mbuf + (size_t)sl * per;
    for (int i = i0 + t; i < i1; i += BLK) {
        int pe = src[i];
        ewc[pe >> 2] = (uint8_t)(pe & 3);
    }
}

// kB2: 16 node-buckets per block. Tile cnt through LDS with coalesced 64B
// reads, scan over chunks, write offTT TRANSPOSED for sequential kC reads.
__global__ void kB2(const int* __restrict__ cnt, int* __restrict__ offTT,
                    int* __restrict__ tot, int NB) {
    __shared__ int tile[NCHUNK * 16];     // 32KB
    __shared__ int segs[16][17];
    int t = threadIdx.x;
    int b0 = blockIdx.x * 16;
    for (int idx = t; idx < NCHUNK * 16; idx += BLK) {
        int c = idx >> 4, b = idx & 15;
        tile[idx] = (b0 + b < NB) ? cnt[(size_t)c * NB + b0 + b] : 0;
    }
    __syncthreads();
    int b = t & 15, seg = t >> 4;         // 16 segs x 16 buckets
    int psum = 0;
#pragma unroll
    for (int k = 0; k < 32; ++k) psum += tile[(seg * 32 + k) * 16 + b];
    segs[seg][b] = psum;
    __syncthreads();
    int ex = 0;
    for (int ss = 0; ss < seg; ++ss) ex += segs[ss][b];
    int run = ex;
#pragma unroll
    for (int k = 0; k < 32; ++k) {
        int c = seg * 32 + k;
        if (b0 + b < NB) offTT[(size_t)c * NB + b0 + b] = run;
        run += tile[c * 16 + b];
    }
    if (seg == 15 && b0 + b < NB) tot[b0 + b] = run;
}

// kBase3: fused. Blocks 0..7: fold emb through gcn (Wfull, hWbias).
// Block 8: exclusive scan of tot[NB] -> base_[0..NB].
__global__ void kBase3(const int* __restrict__ tot, int* __restrict__ base_, int NB,
                       const float* __restrict__ emb_W, const float* __restrict__ emb_b,
                       const float* __restrict__ gcn_W,
                       float* __restrict__ Wfull, float* __restrict__ hWbias) {
    int t = threadIdx.x;
    if (blockIdx.x < 8) {
        int k = blockIdx.x * 8 + (t >> 5), j = t & 31;
        float acc;
        if (k == 0) {
            acc = gcn_W[j];
        } else {
            int m = k - 1;
            acc = 0.0f;
#pragma unroll 9
            for (int tt = 0; tt < 63; ++tt)
                acc += emb_W[m * 63 + tt] * gcn_W[(1 + tt) * 32 + j];
        }
        Wfull[k * 32 + j] = acc;
        if (blockIdx.x == 0 && t < 32) {
            float bacc = 0.0f;
            for (int tt = 0; tt < 63; ++tt)
                bacc += emb_b[tt] * gcn_W[(1 + tt) * 32 + t];
            hWbias[t] = bacc;
        }
    } else {
        __shared__ int s[BLK];
        const int K = 7;  // 256*7 = 1792 >= MAXNB
        int v[K]; int sum = 0;
#pragma unroll
        for (int k = 0; k < K; ++k) {
            int i = t * K + k;
            v[k] = (i < NB) ? tot[i] : 0;
            sum += v[k];
        }
        s[t] = sum; __syncthreads();
        for (int st = 1; st < BLK; st <<= 1) {
            int x = (t >= st) ? s[t - st] : 0;
            __syncthreads(); s[t] += x; __syncthreads();
        }
        int ex = (t == 0) ? 0 : s[t - 1];
#pragma unroll
        for (int k = 0; k < K; ++k) {
            int i = t * K + k;
            if (i < NB) base_[i] = ex;
            ex += v[k];
        }
        if (t == BLK - 1) base_[NB] = s[BLK - 1];
    }
}

// kC: 8-slice XCD-partitioned scatter (R8-proven). slice = blockIdx&7 ->
// exactly ONE XCD owns each csrB region (~1.5MB, L2-resident).
// Entry = (local_col<<19)|(row<<2)|cls.
__global__ void kC_scatter(const int* __restrict__ row, const int* __restrict__ col,
                           const uint8_t* __restrict__ ewc, const int* __restrict__ base_,
                           const int* __restrict__ offTT, int* __restrict__ csrB,
                           int n_edges, int NB, int nbs) {
    __shared__ int cur[200];
    int sl = blockIdx.x & 7, c = blockIdx.x >> 3, t = threadIdx.x;
    int b0 = sl * nbs, b1 = min(b0 + nbs, NB);
    const int* offrow = offTT + (size_t)c * NB;
    for (int b = b0 + t; b < b1; b += BLK)
        cur[b - b0] = base_[b] + offrow[b];
    __syncthreads();
    int chunk = (n_edges + NCHUNK - 1) / NCHUNK;
    int e0 = c * chunk, e1 = min(e0 + chunk, n_edges);
    for (int e = e0 + t; e < e1; e += BLK) {
        int cc = col[e]; int b = cc >> 6;
        if (b >= b0 && b < b1) {
            int pos = atomicAdd(&cur[b - b0], 1);
            csrB[pos] = ((cc & 63) << 19) | (row[e] << 2) | (ewc[e] & 3);
        }
    }
}

// k4f: fused degree + GEMM per 64-node bucket.
__global__ void k4f_gemm(const float* __restrict__ x, const float* __restrict__ Wfull,
                         const float* __restrict__ hWbias, const int* __restrict__ base_,
                         const int* __restrict__ csrB, const float* __restrict__ mw,
                         __half* __restrict__ hWs, int n_nodes) {
    __shared__ float Wl[64 * 32];      // 8KB
    __shared__ float xs[64 * 64];      // 16KB
    __shared__ int ct4[256];           // 1KB
    __shared__ float dv[64];
    int b = blockIdx.x, t = threadIdx.x;
    for (int idx = t; idx < 2048; idx += BLK) Wl[idx] = Wfull[idx];
    if (t < 256) ct4[t] = 0;
    int rowBase = b * 64;
    for (int idx = t; idx < 4096; idx += BLK) {
        int r = rowBase + (idx >> 6);
        xs[idx] = (r < n_nodes) ? x[(size_t)r * 64 + (idx & 63)] : 0.0f;
    }
    __syncthreads();
    int p0 = base_[b], p1 = base_[b + 1];
    for (int p = p0 + t; p < p1; p += BLK) {
        int e = csrB[p];
        atomicAdd(&ct4[((e >> 19) << 2) | (e & 3)], 1);
    }
    __syncthreads();
    if (t < 64) {
        float a = mw[0], bb = mw[1], c3 = mw[2];
        float m = fmaxf(a, fmaxf(bb, c3));
        float ea = __expf(a - m), eb = __expf(bb - m), ec = __expf(c3 - m);
        float inv = 1.0f / (ea + eb + ec);
        float deg = (ea * inv) * (float)ct4[t * 4]
                  + (eb * inv) * (float)ct4[t * 4 + 1]
                  + (ec * inv) * (float)ct4[t * 4 + 2]
                  + (float)ct4[t * 4 + 3]
                  + 1.0f;
        dv[t] = rsqrtf(deg);
    }
    __syncthreads();
    int j = t & 31, lr = t >> 5;
#pragma unroll
    for (int k8 = 0; k8 < 8; ++k8) {
        int r = lr + 8 * k8;
        int n = rowBase + r;
        if (n < n_nodes) {
            float acc = hWbias[j];
#pragma unroll
            for (int k = 0; k < 64; ++k)
                acc += xs[r * 64 + k] * Wl[k * 32 + j];
            hWs[(size_t)n * 32 + j] = __float2half(dv[r] * acc);
        }
    }
}

// kD: per-bucket consumer. Counting-sort edges into LDS per-node lists,
// per-node register gather (16 lanes/node, half2, 8 loads in flight),
// relu, run-length pool.
__global__ void kD_gather(const int* __restrict__ base_, const int* __restrict__ csrB,
                          const __half2* __restrict__ hws2,
                          const float* __restrict__ mw, const float* __restrict__ gcn_b,
                          const int* __restrict__ batch, float* __restrict__ pooled,
                          int n_nodes) {
    __shared__ int ent[ENTCAP];
    __shared__ float res[64 * 33];
    __shared__ int ct4[256];
    __shared__ int ct[64], st[64], cur[64];
    __shared__ float dl[64], gb[32];
    __shared__ int bl[64];
    int b = blockIdx.x, t = threadIdx.x;
    if (t < 256) ct4[t] = 0;
    if (t < 64) {
        int n = b * 64 + t;
        bl[t] = (n < n_nodes) ? batch[n] : -1;
    }
    if (t < 32) gb[t] = gcn_b[t];
    __syncthreads();
    int p0 = base_[b], p1 = base_[b + 1];
    int m = min(p1 - p0, ENTCAP);     // clamp (14 sigma margin, never hit)
    int p1c = p0 + m;
    for (int p = p0 + t; p < p1c; p += BLK) {
        int e = csrB[p];
        atomicAdd(&ct4[((e >> 19) << 2) | (e & 3)], 1);
    }
    __syncthreads();
    float a = mw[0], bb = mw[1], c3 = mw[2];
    float mx = fmaxf(a, fmaxf(bb, c3));
    float ea = __expf(a - mx), eb = __expf(bb - mx), ec = __expf(c3 - mx);
    float inv = 1.0f / (ea + eb + ec);
    float w0 = ea * inv, w1 = eb * inv, w2 = ec * inv;
    if (t < 64) {
        int c0 = ct4[t * 4], c1 = ct4[t * 4 + 1], c2 = ct4[t * 4 + 2], c33 = ct4[t * 4 + 3];
        ct[t] = c0 + c1 + c2 + c33;
        dl[t] = rsqrtf(w0 * (float)c0 + w1 * (float)c1 + w2 * (float)c2
                       + (float)c33 + 1.0f);
    }
    __syncthreads();
    if (t < 64) st[t] = ct[t];
    __syncthreads();
    for (int off = 1; off < 64; off <<= 1) {
        int v = (t < 64 && t >= off) ? st[t - off] : 0;
        __syncthreads();
        if (t < 64) st[t] += v;
        __syncthreads();
    }
    if (t < 64) { st[t] -= ct[t]; cur[t] = st[t]; }
    __syncthreads();
    for (int p = p0 + t; p < p1c; p += BLK) {
        int e = csrB[p];
        int pos = atomicAdd(&cur[e >> 19], 1);
        ent[pos] = e;
    }
    __syncthreads();
    int grp = t >> 4, j2 = t & 15;
#pragma unroll
    for (int idx = 0; idx < 4; ++idx) {
        int lc = grp + 16 * idx;
        int n = b * 64 + lc;
        float rx = 0.0f, ry = 0.0f;
        if (n < n_nodes) {
            int s = st[lc], end = s + ct[lc];
            float ax = 0.0f, ay = 0.0f;
            int p = s;
            for (; p + 8 <= end; p += 8) {
                int e0 = ent[p],     e1 = ent[p + 1], e2 = ent[p + 2], e3 = ent[p + 3];
                int e4 = ent[p + 4], e5 = ent[p + 5], e6 = ent[p + 6], e7 = ent[p + 7];
                __half2 h0 = hws2[(size_t)((e0 >> 2) & 0x1FFFF) * 16 + j2];
                __half2 h1 = hws2[(size_t)((e1 >> 2) & 0x1FFFF) * 16 + j2];
                __half2 h2 = hws2[(size_t)((e2 >> 2) & 0x1FFFF) * 16 + j2];
                __half2 h3 = hws2[(size_t)((e3 >> 2) & 0x1FFFF) * 16 + j2];
                __half2 h4 = hws2[(size_t)((e4 >> 2) & 0x1FFFF) * 16 + j2];
                __half2 h5 = hws2[(size_t)((e5 >> 2) & 0x1FFFF) * 16 + j2];
                __half2 h6 = hws2[(size_t)((e6 >> 2) & 0x1FFFF) * 16 + j2];
                __half2 h7 = hws2[(size_t)((e7 >> 2) & 0x1FFFF) * 16 + j2];
                float f0 = ((e0 & 3) == 0) ? w0 : (((e0 & 3) == 1) ? w1 : w2);
                float f1 = ((e1 & 3) == 0) ? w0 : (((e1 & 3) == 1) ? w1 : w2);
                float f2 = ((e2 & 3) == 0) ? w0 : (((e2 & 3) == 1) ? w1 : w2);
                float f3 = ((e3 & 3) == 0) ? w0 : (((e3 & 3) == 1) ? w1 : w2);
                float f4 = ((e4 & 3) == 0) ? w0 : (((e4 & 3) == 1) ? w1 : w2);
                float f5 = ((e5 & 3) == 0) ? w0 : (((e5 & 3) == 1) ? w1 : w2);
                float f6 = ((e6 & 3) == 0) ? w0 : (((e6 & 3) == 1) ? w1 : w2);
                float f7 = ((e7 & 3) == 0) ? w0 : (((e7 & 3) == 1) ? w1 : w2);
                float2 g0 = __half22float2(h0), g1 = __half22float2(h1);
                float2 g2 = __half22float2(h2), g3 = __half22float2(h3);
                float2 g4 = __half22float2(h4), g5 = __half22float2(h5);
                float2 g6 = __half22float2(h6), g7 = __half22float2(h7);
                ax += f0 * g0.x + f1 * g1.x + f2 * g2.x + f3 * g3.x
                    + f4 * g4.x + f5 * g5.x + f6 * g6.x + f7 * g7.x;
                ay += f0 * g0.y + f1 * g1.y + f2 * g2.y + f3 * g3.y
                    + f4 * g4.y + f5 * g5.y + f6 * g6.y + f7 * g7.y;
            }
            for (; p < end; ++p) {
                int e0 = ent[p];
                __half2 h0 = hws2[(size_t)((e0 >> 2) & 0x1FFFF) * 16 + j2];
                float f0 = ((e0 & 3) == 0) ? w0 : (((e0 & 3) == 1) ? w1 : w2);
                float2 g0 = __half22float2(h0);
                ax += f0 * g0.x; ay += f0 * g0.y;
            }
            float2 self = __half22float2(hws2[(size_t)n * 16 + j2]);
            float di = dl[lc];
            rx = fmaxf(di * (ax + self.x) + gb[2 * j2], 0.0f);
            ry = fmaxf(di * (ay + self.y) + gb[2 * j2 + 1], 0.0f);
        }
        res[lc * 33 + 2 * j2]     = rx;
        res[lc * 33 + 2 * j2 + 1] = ry;
    }
    __syncthreads();
    if (t < 32) {
        int j = t;
        float sum = 0.0f; int g0 = bl[0];
        for (int lc = 0; lc < 64; ++lc) {
            if (bl[lc] < 0) break;
            float val = res[lc * 33 + j];
            if (bl[lc] != g0) { atomicAdd(&pooled[g0 * 32 + j], sum); sum = 0.0f; g0 = bl[lc]; }
            sum += val;
        }
        if (g0 >= 0) atomicAdd(&pooled[g0 * 32 + j], sum);
    }
}

// k7: head: z = relu(pooled @ fc1_W + fc1_b); out = z @ out_W + out_b
__global__ void k7_head(const float* __restrict__ pooled, const float* __restrict__ fc1_W,
                        const float* __restrict__ fc1_b, const float* __restrict__ out_W,
                        const float* __restrict__ out_b, float* __restrict__ out,
                        int n_graphs) {
    __shared__ float Wl[32 * 32];
    __shared__ float bl[32];
    __shared__ float owl[32];
    int t = threadIdx.x;
    for (int idx = t; idx < 1024; idx += BLK) Wl[idx] = fc1_W[idx];
    if (t < 32) { bl[t] = fc1_b[t]; owl[t] = out_W[t]; }
    __syncthreads();
    if (t < n_graphs) {
        float p[32];
#pragma unroll
        for (int k = 0; k < 32; ++k) p[k] = pooled[t * 32 + k];
        float acc = 0.0f;
        for (int j = 0; j < 32; ++j) {
            float z = bl[j];
#pragma unroll
            for (int k = 0; k < 32; ++k) z += p[k] * Wl[k * 32 + j];
            z = fmaxf(z, 0.0f);
            acc += z * owl[j];
        }
        out[t] = acc + out_b[0];
    }
}

static inline size_t align_up(size_t v, size_t a) { return (v + a - 1) & ~(a - 1); }

extern "C" void kernel_launch(void* const* d_in, const int* in_sizes, int n_in,
                              void* d_out, int out_size, void* d_ws, size_t ws_size,
                              hipStream_t stream) {
    const float* x     = (const float*)d_in[0];
    const int*   ei    = (const int*)d_in[1];
    const int*   batch = (const int*)d_in[2];
    const int*   km    = (const int*)d_in[3];
    const int*   um    = (const int*)d_in[4];
    const int*   om    = (const int*)d_in[5];
    const float* mw    = (const float*)d_in[6];
    const float* emb_W = (const float*)d_in[7];
    const float* emb_b = (const float*)d_in[8];
    const float* gcn_W = (const float*)d_in[9];
    const float* gcn_b = (const float*)d_in[10];
    const float* fc1_W = (const float*)d_in[11];
    const float* fc1_b = (const float*)d_in[12];
    const float* out_W = (const float*)d_in[13];
    const float* out_b = (const float*)d_in[14];

    const int n_nodes  = in_sizes[0] / 64;
    const int n_edges  = in_sizes[1] / 2;
    const int s0 = in_sizes[3], s1 = in_sizes[4], s2 = in_sizes[5];
    const int n_graphs = out_size;  // 256

    const int* row = ei;
    const int* col = ei + n_edges;

    const int NB  = (n_nodes + 63) >> 6;   // 1563 buckets of 64 nodes
    const int NGB = (NB + 15) / 16;        // kB2 blocks
    const int nbs = (NB + 7) / 8;          // buckets per slice (8 slices)
    const int per = (n_edges + 7) / 8;     // edge-range slice width

    // ---- workspace layout (~28.3 MB) ----
    char* base = (char*)d_ws;
    float*   pooled = (float*)base;   base += (size_t)n_graphs * 32 * 4;   // } zeroed
    int*     gcur   = (int*)base;     base += 8 * 4;                       // } together
    int*     cnt    = (int*)base;     base += (size_t)NCHUNK * NB * 4;     // 3.2 MB
    int*     offTT  = (int*)base;     base += (size_t)NCHUNK * NB * 4;     // 3.2 MB
    int*     tot    = (int*)base;     base += (size_t)NB * 4;
    int*     base_  = (int*)base;     base += (size_t)(NB + 1) * 4;
    float*   Wfull  = (float*)base;   base += 2048 * 4;
    float*   hWbias = (float*)base;   base += 32 * 4;
    uint8_t* ewc    = (uint8_t*)base; base += align_up((size_t)n_edges, 64);
    int*     csrB   = (int*)base;     base += (size_t)8 * per * 4;         // 12 MB
    base = (char*)align_up((size_t)base, 64);
    __half*  hWs    = (__half*)base;  base += (size_t)n_nodes * 32 * 2;    // 6.4 MB

    int* mbuf = csrB;   // phase-1 mask buckets alias csrB (dead until kC)

    hipMemsetAsync(pooled, 0, (size_t)n_graphs * 32 * 4 + 8 * 4, stream);

    kA1<<<NCHUNK + 256, BLK, 0, stream>>>(col, cnt, n_edges, NB,
                                          km, um, om, s0, s1, s2, gcur, mbuf, per);
    kE_ewc<<<256, BLK, 0, stream>>>(gcur, mbuf, ewc, per);
    kB2<<<NGB, BLK, 0, stream>>>(cnt, offTT, tot, NB);
    kBase3<<<9, BLK, 0, stream>>>(tot, base_, NB, emb_W, emb_b, gcn_W, Wfull, hWbias);
    kC_scatter<<<NCHUNK * 8, BLK, 0, stream>>>(row, col, ewc, base_, offTT, csrB,
                                               n_edges, NB, nbs);
    k4f_gemm<<<NB, BLK, 0, stream>>>(x, Wfull, hWbias, base_, csrB, mw, hWs, n_nodes);
    kD_gather<<<NB, BLK, 0, stream>>>(base_, csrB, (const __half2*)hWs, mw,
                                      gcn_b, batch, pooled, n_nodes);
    k7_head<<<1, BLK, 0, stream>>>(pooled, fc1_W, fc1_b, out_W, out_b, (float*)d_out, n_graphs);
}

// Round 13
// 280.172 us; speedup vs baseline: 1.2106x; 1.1370x over previous
//
#include <hip/hip_runtime.h>
#include <hip/hip_fp16.h>
#include <stdint.h>

// GCN forward. N=100000, E=3000000, G=256, F_IN=64, NHID=32.
// R1: 96M global scatter-atomics = L2 atomic ceiling (312us) -> gather.
// R2: naive CSR build = 16x write amplification (random sub-line stores,
//     8 incoherent L2s, write-allocate thrash).
// R3/R7/R8: 8-slice XCD build = clean writes but 8x edge re-read (FETCH 107MB).
// R5: LDS atomics ~3.6cyc/op; few-address LDS atomics serialize (R12 radix).
// R6: small hot global atomic arrays = 32B line ping-pong per op.
// R9: nontemporal_store is write-through (~56B per random sub-line store).
// R11: slicing ewc scatter: clean writes but 8x mask re-read cost more.
//     Random sub-line stores are fire-and-forget; re-READS stall.
// R12: radix mask inversion lost to double mask read + 8-address LDS atomic
//     serialization. Reverted to R10 plain byte stores.
// R13: kC SINGLE PASS via XCD-grouped chunk remap: chunk=(blk&7)*64+(blk>>3)
//     puts chunks 0-63 on XCD0, 64-127 on XCD1, ... csrB positions are
//     monotone in chunk, so each XCD writes contiguous ~960B sub-runs per
//     bucket -> clean writes AND edges read once.

#define BLK 256
#define NCHUNK 512          // edge chunks for count/scatter
#define MAXNB 1600          // max buckets (N<=102400)
#define ENTCAP 2560         // per-bucket LDS entries (lambda=1920, 14 sigma)

// kA1: fused. Blocks [0,NCHUNK): per-chunk node-bucket histogram (LDS).
// Blocks [NCHUNK, NCHUNK+128): edge class from masks, plain byte stores
// (fire-and-forget; write-BW bound, proven best overall in R10).
__global__ void kA1(const int* __restrict__ col, int* __restrict__ cnt,
                    int n_edges, int NB,
                    const int* __restrict__ km, const int* __restrict__ um,
                    const int* __restrict__ om, int s0, int s1, int s2,
                    uint8_t* __restrict__ ewc) {
    int t = threadIdx.x;
    if (blockIdx.x < NCHUNK) {
        __shared__ int lh[MAXNB];
        int c = blockIdx.x;
        for (int b = t; b < NB; b += BLK) lh[b] = 0;
        __syncthreads();
        int chunk = (n_edges + NCHUNK - 1) / NCHUNK;
        int e0 = c * chunk, e1 = min(e0 + chunk, n_edges);
        for (int e = e0 + t; e < e1; e += BLK) atomicAdd(&lh[col[e] >> 6], 1);
        __syncthreads();
        for (int b = t; b < NB; b += BLK) cnt[(size_t)c * NB + b] = lh[b];
    } else {
        int gid = (blockIdx.x - NCHUNK) * BLK + t;
        int total = s0 + s1 + s2;
        for (int i = gid; i < total; i += 128 * BLK) {
            int e; uint8_t cls;
            if (i < s0)           { e = km[i];           cls = 0; }
            else if (i < s0 + s1) { e = um[i - s0];      cls = 1; }
            else                  { e = om[i - s0 - s1]; cls = 2; }
            ewc[e] = cls;
        }
    }
}

// kB2: 16 node-buckets per block. Tile cnt through LDS with coalesced 64B
// reads, scan over chunks, write offTT TRANSPOSED for sequential kC reads.
__global__ void kB2(const int* __restrict__ cnt, int* __restrict__ offTT,
                    int* __restrict__ tot, int NB) {
    __shared__ int tile[NCHUNK * 16];     // 32KB
    __shared__ int segs[16][17];
    int t = threadIdx.x;
    int b0 = blockIdx.x * 16;
    for (int idx = t; idx < NCHUNK * 16; idx += BLK) {
        int c = idx >> 4, b = idx & 15;
        tile[idx] = (b0 + b < NB) ? cnt[(size_t)c * NB + b0 + b] : 0;
    }
    __syncthreads();
    int b = t & 15, seg = t >> 4;         // 16 segs x 16 buckets
    int psum = 0;
#pragma unroll
    for (int k = 0; k < 32; ++k) psum += tile[(seg * 32 + k) * 16 + b];
    segs[seg][b] = psum;
    __syncthreads();
    int ex = 0;
    for (int ss = 0; ss < seg; ++ss) ex += segs[ss][b];
    int run = ex;
#pragma unroll
    for (int k = 0; k < 32; ++k) {
        int c = seg * 32 + k;
        if (b0 + b < NB) offTT[(size_t)c * NB + b0 + b] = run;
        run += tile[c * 16 + b];
    }
    if (seg == 15 && b0 + b < NB) tot[b0 + b] = run;
}

// kBase3: fused. Blocks 0..7: fold emb through gcn (Wfull, hWbias).
// Block 8: exclusive scan of tot[NB] -> base_[0..NB].
__global__ void kBase3(const int* __restrict__ tot, int* __restrict__ base_, int NB,
                       const float* __restrict__ emb_W, const float* __restrict__ emb_b,
                       const float* __restrict__ gcn_W,
                       float* __restrict__ Wfull, float* __restrict__ hWbias) {
    int t = threadIdx.x;
    if (blockIdx.x < 8) {
        int k = blockIdx.x * 8 + (t >> 5), j = t & 31;
        float acc;
        if (k == 0) {
            acc = gcn_W[j];
        } else {
            int m = k - 1;
            acc = 0.0f;
#pragma unroll 9
            for (int tt = 0; tt < 63; ++tt)
                acc += emb_W[m * 63 + tt] * gcn_W[(1 + tt) * 32 + j];
        }
        Wfull[k * 32 + j] = acc;
        if (blockIdx.x == 0 && t < 32) {
            float bacc = 0.0f;
            for (int tt = 0; tt < 63; ++tt)
                bacc += emb_b[tt] * gcn_W[(1 + tt) * 32 + t];
            hWbias[t] = bacc;
        }
    } else {
        __shared__ int s[BLK];
        const int K = 7;  // 256*7 = 1792 >= MAXNB
        int v[K]; int sum = 0;
#pragma unroll
        for (int k = 0; k < K; ++k) {
            int i = t * K + k;
            v[k] = (i < NB) ? tot[i] : 0;
            sum += v[k];
        }
        s[t] = sum; __syncthreads();
        for (int st = 1; st < BLK; st <<= 1) {
            int x = (t >= st) ? s[t - st] : 0;
            __syncthreads(); s[t] += x; __syncthreads();
        }
        int ex = (t == 0) ? 0 : s[t - 1];
#pragma unroll
        for (int k = 0; k < K; ++k) {
            int i = t * K + k;
            if (i < NB) base_[i] = ex;
            ex += v[k];
        }
        if (t == BLK - 1) base_[NB] = s[BLK - 1];
    }
}

// kC: SINGLE-PASS scatter with XCD-grouped chunk remap.
// chunk = (blockIdx&7)*(NCHUNK/8) + (blockIdx>>3): XCD k processes chunks
// [k*64,(k+1)*64) -> each bucket's csrB segment is written as 8 contiguous
// per-XCD sub-runs (monotone offsets in chunk) -> no cross-XCD line sharing
// except sub-run boundaries. Edges read ONCE. All-bucket LDS cursors.
// Entry = (local_col<<19)|(row<<2)|cls.
__global__ void kC_scatter(const int* __restrict__ row, const int* __restrict__ col,
                           const uint8_t* __restrict__ ewc, const int* __restrict__ base_,
                           const int* __restrict__ offTT, int* __restrict__ csrB,
                           int n_edges, int NB) {
    __shared__ int cur[MAXNB];
    int t = threadIdx.x;
    int c = (blockIdx.x & 7) * (NCHUNK / 8) + (blockIdx.x >> 3);
    const int* offrow = offTT + (size_t)c * NB;
    for (int b = t; b < NB; b += BLK) cur[b] = base_[b] + offrow[b];
    __syncthreads();
    int chunk = (n_edges + NCHUNK - 1) / NCHUNK;
    int e0 = c * chunk, e1 = min(e0 + chunk, n_edges);
    for (int e = e0 + t; e < e1; e += BLK) {
        int cc = col[e];
        int pos = atomicAdd(&cur[cc >> 6], 1);
        csrB[pos] = ((cc & 63) << 19) | (row[e] << 2) | (ewc[e] & 3);
    }
}

// k4f: fused degree + GEMM per 64-node bucket.
__global__ void k4f_gemm(const float* __restrict__ x, const float* __restrict__ Wfull,
                         const float* __restrict__ hWbias, const int* __restrict__ base_,
                         const int* __restrict__ csrB, const float* __restrict__ mw,
                         __half* __restrict__ hWs, int n_nodes) {
    __shared__ float Wl[64 * 32];      // 8KB
    __shared__ float xs[64 * 64];      // 16KB
    __shared__ int ct4[256];           // 1KB
    __shared__ float dv[64];
    int b = blockIdx.x, t = threadIdx.x;
    for (int idx = t; idx < 2048; idx += BLK) Wl[idx] = Wfull[idx];
    if (t < 256) ct4[t] = 0;
    int rowBase = b * 64;
    for (int idx = t; idx < 4096; idx += BLK) {
        int r = rowBase + (idx >> 6);
        xs[idx] = (r < n_nodes) ? x[(size_t)r * 64 + (idx & 63)] : 0.0f;
    }
    __syncthreads();
    int p0 = base_[b], p1 = base_[b + 1];
    for (int p = p0 + t; p < p1; p += BLK) {
        int e = csrB[p];
        atomicAdd(&ct4[((e >> 19) << 2) | (e & 3)], 1);
    }
    __syncthreads();
    if (t < 64) {
        float a = mw[0], bb = mw[1], c3 = mw[2];
        float m = fmaxf(a, fmaxf(bb, c3));
        float ea = __expf(a - m), eb = __expf(bb - m), ec = __expf(c3 - m);
        float inv = 1.0f / (ea + eb + ec);
        float deg = (ea * inv) * (float)ct4[t * 4]
                  + (eb * inv) * (float)ct4[t * 4 + 1]
                  + (ec * inv) * (float)ct4[t * 4 + 2]
                  + (float)ct4[t * 4 + 3]
                  + 1.0f;
        dv[t] = rsqrtf(deg);
    }
    __syncthreads();
    int j = t & 31, lr = t >> 5;
#pragma unroll
    for (int k8 = 0; k8 < 8; ++k8) {
        int r = lr + 8 * k8;
        int n = rowBase + r;
        if (n < n_nodes) {
            float acc = hWbias[j];
#pragma unroll
            for (int k = 0; k < 64; ++k)
                acc += xs[r * 64 + k] * Wl[k * 32 + j];
            hWs[(size_t)n * 32 + j] = __float2half(dv[r] * acc);
        }
    }
}

// kD: per-bucket consumer. Counting-sort edges into LDS per-node lists,
// per-node register gather (16 lanes/node, half2, 8 loads in flight),
// relu, run-length pool.
__global__ void kD_gather(const int* __restrict__ base_, const int* __restrict__ csrB,
                          const __half2* __restrict__ hws2,
                          const float* __restrict__ mw, const float* __restrict__ gcn_b,
                          const int* __restrict__ batch, float* __restrict__ pooled,
                          int n_nodes) {
    __shared__ int ent[ENTCAP];
    __shared__ float res[64 * 33];
    __shared__ int ct4[256];
    __shared__ int ct[64], st[64], cur[64];
    __shared__ float dl[64], gb[32];
    __shared__ int bl[64];
    int b = blockIdx.x, t = threadIdx.x;
    if (t < 256) ct4[t] = 0;
    if (t < 64) {
        int n = b * 64 + t;
        bl[t] = (n < n_nodes) ? batch[n] : -1;
    }
    if (t < 32) gb[t] = gcn_b[t];
    __syncthreads();
    int p0 = base_[b], p1 = base_[b + 1];
    int m = min(p1 - p0, ENTCAP);     // clamp (14 sigma margin, never hit)
    int p1c = p0 + m;
    for (int p = p0 + t; p < p1c; p += BLK) {
        int e = csrB[p];
        atomicAdd(&ct4[((e >> 19) << 2) | (e & 3)], 1);
    }
    __syncthreads();
    float a = mw[0], bb = mw[1], c3 = mw[2];
    float mx = fmaxf(a, fmaxf(bb, c3));
    float ea = __expf(a - mx), eb = __expf(bb - mx), ec = __expf(c3 - mx);
    float inv = 1.0f / (ea + eb + ec);
    float w0 = ea * inv, w1 = eb * inv, w2 = ec * inv;
    if (t < 64) {
        int c0 = ct4[t * 4], c1 = ct4[t * 4 + 1], c2 = ct4[t * 4 + 2], c33 = ct4[t * 4 + 3];
        ct[t] = c0 + c1 + c2 + c33;
        dl[t] = rsqrtf(w0 * (float)c0 + w1 * (float)c1 + w2 * (float)c2
                       + (float)c33 + 1.0f);
    }
    __syncthreads();
    if (t < 64) st[t] = ct[t];
    __syncthreads();
    for (int off = 1; off < 64; off <<= 1) {
        int v = (t < 64 && t >= off) ? st[t - off] : 0;
        __syncthreads();
        if (t < 64) st[t] += v;
        __syncthreads();
    }
    if (t < 64) { st[t] -= ct[t]; cur[t] = st[t]; }
    __syncthreads();
    for (int p = p0 + t; p < p1c; p += BLK) {
        int e = csrB[p];
        int pos = atomicAdd(&cur[e >> 19], 1);
        ent[pos] = e;
    }
    __syncthreads();
    int grp = t >> 4, j2 = t & 15;
#pragma unroll
    for (int idx = 0; idx < 4; ++idx) {
        int lc = grp + 16 * idx;
        int n = b * 64 + lc;
        float rx = 0.0f, ry = 0.0f;
        if (n < n_nodes) {
            int s = st[lc], end = s + ct[lc];
            float ax = 0.0f, ay = 0.0f;
            int p = s;
            for (; p + 8 <= end; p += 8) {
                int e0 = ent[p],     e1 = ent[p + 1], e2 = ent[p + 2], e3 = ent[p + 3];
                int e4 = ent[p + 4], e5 = ent[p + 5], e6 = ent[p + 6], e7 = ent[p + 7];
                __half2 h0 = hws2[(size_t)((e0 >> 2) & 0x1FFFF) * 16 + j2];
                __half2 h1 = hws2[(size_t)((e1 >> 2) & 0x1FFFF) * 16 + j2];
                __half2 h2 = hws2[(size_t)((e2 >> 2) & 0x1FFFF) * 16 + j2];
                __half2 h3 = hws2[(size_t)((e3 >> 2) & 0x1FFFF) * 16 + j2];
                __half2 h4 = hws2[(size_t)((e4 >> 2) & 0x1FFFF) * 16 + j2];
                __half2 h5 = hws2[(size_t)((e5 >> 2) & 0x1FFFF) * 16 + j2];
                __half2 h6 = hws2[(size_t)((e6 >> 2) & 0x1FFFF) * 16 + j2];
                __half2 h7 = hws2[(size_t)((e7 >> 2) & 0x1FFFF) * 16 + j2];
                float f0 = ((e0 & 3) == 0) ? w0 : (((e0 & 3) == 1) ? w1 : w2);
                float f1 = ((e1 & 3) == 0) ? w0 : (((e1 & 3) == 1) ? w1 : w2);
                float f2 = ((e2 & 3) == 0) ? w0 : (((e2 & 3) == 1) ? w1 : w2);
                float f3 = ((e3 & 3) == 0) ? w0 : (((e3 & 3) == 1) ? w1 : w2);
                float f4 = ((e4 & 3) == 0) ? w0 : (((e4 & 3) == 1) ? w1 : w2);
                float f5 = ((e5 & 3) == 0) ? w0 : (((e5 & 3) == 1) ? w1 : w2);
                float f6 = ((e6 & 3) == 0) ? w0 : (((e6 & 3) == 1) ? w1 : w2);
                float f7 = ((e7 & 3) == 0) ? w0 : (((e7 & 3) == 1) ? w1 : w2);
                float2 g0 = __half22float2(h0), g1 = __half22float2(h1);
                float2 g2 = __half22float2(h2), g3 = __half22float2(h3);
                float2 g4 = __half22float2(h4), g5 = __half22float2(h5);
                float2 g6 = __half22float2(h6), g7 = __half22float2(h7);
                ax += f0 * g0.x + f1 * g1.x + f2 * g2.x + f3 * g3.x
                    + f4 * g4.x + f5 * g5.x + f6 * g6.x + f7 * g7.x;
                ay += f0 * g0.y + f1 * g1.y + f2 * g2.y + f3 * g3.y
                    + f4 * g4.y + f5 * g5.y + f6 * g6.y + f7 * g7.y;
            }
            for (; p < end; ++p) {
                int e0 = ent[p];
                __half2 h0 = hws2[(size_t)((e0 >> 2) & 0x1FFFF) * 16 + j2];
                float f0 = ((e0 & 3) == 0) ? w0 : (((e0 & 3) == 1) ? w1 : w2);
                float2 g0 = __half22float2(h0);
                ax += f0 * g0.x; ay += f0 * g0.y;
            }
            float2 self = __half22float2(hws2[(size_t)n * 16 + j2]);
            float di = dl[lc];
            rx = fmaxf(di * (ax + self.x) + gb[2 * j2], 0.0f);
            ry = fmaxf(di * (ay + self.y) + gb[2 * j2 + 1], 0.0f);
        }
        res[lc * 33 + 2 * j2]     = rx;
        res[lc * 33 + 2 * j2 + 1] = ry;
    }
    __syncthreads();
    if (t < 32) {
        int j = t;
        float sum = 0.0f; int g0 = bl[0];
        for (int lc = 0; lc < 64; ++lc) {
            if (bl[lc] < 0) break;
            float val = res[lc * 33 + j];
            if (bl[lc] != g0) { atomicAdd(&pooled[g0 * 32 + j], sum); sum = 0.0f; g0 = bl[lc]; }
            sum += val;
        }
        if (g0 >= 0) atomicAdd(&pooled[g0 * 32 + j], sum);
    }
}

// k7: head: z = relu(pooled @ fc1_W + fc1_b); out = z @ out_W + out_b
__global__ void k7_head(const float* __restrict__ pooled, const float* __restrict__ fc1_W,
                        const float* __restrict__ fc1_b, const float* __restrict__ out_W,
                        const float* __restrict__ out_b, float* __restrict__ out,
                        int n_graphs) {
    __shared__ float Wl[32 * 32];
    __shared__ float bl[32];
    __shared__ float owl[32];
    int t = threadIdx.x;
    for (int idx = t; idx < 1024; idx += BLK) Wl[idx] = fc1_W[idx];
    if (t < 32) { bl[t] = fc1_b[t]; owl[t] = out_W[t]; }
    __syncthreads();
    if (t < n_graphs) {
        float p[32];
#pragma unroll
        for (int k = 0; k < 32; ++k) p[k] = pooled[t * 32 + k];
        float acc = 0.0f;
        for (int j = 0; j < 32; ++j) {
            float z = bl[j];
#pragma unroll
            for (int k = 0; k < 32; ++k) z += p[k] * Wl[k * 32 + j];
            z = fmaxf(z, 0.0f);
            acc += z * owl[j];
        }
        out[t] = acc + out_b[0];
    }
}

static inline size_t align_up(size_t v, size_t a) { return (v + a - 1) & ~(a - 1); }

extern "C" void kernel_launch(void* const* d_in, const int* in_sizes, int n_in,
                              void* d_out, int out_size, void* d_ws, size_t ws_size,
                              hipStream_t stream) {
    const float* x     = (const float*)d_in[0];
    const int*   ei    = (const int*)d_in[1];
    const int*   batch = (const int*)d_in[2];
    const int*   km    = (const int*)d_in[3];
    const int*   um    = (const int*)d_in[4];
    const int*   om    = (const int*)d_in[5];
    const float* mw    = (const float*)d_in[6];
    const float* emb_W = (const float*)d_in[7];
    const float* emb_b = (const float*)d_in[8];
    const float* gcn_W = (const float*)d_in[9];
    const float* gcn_b = (const float*)d_in[10];
    const float* fc1_W = (const float*)d_in[11];
    const float* fc1_b = (const float*)d_in[12];
    const float* out_W = (const float*)d_in[13];
    const float* out_b = (const float*)d_in[14];

    const int n_nodes  = in_sizes[0] / 64;
    const int n_edges  = in_sizes[1] / 2;
    const int s0 = in_sizes[3], s1 = in_sizes[4], s2 = in_sizes[5];
    const int n_graphs = out_size;  // 256

    const int* row = ei;
    const int* col = ei + n_edges;

    const int NB  = (n_nodes + 63) >> 6;   // 1563 buckets of 64 nodes
    const int NGB = (NB + 15) / 16;        // kB2 blocks

    // ---- workspace layout (~28.3 MB) ----
    char* base = (char*)d_ws;
    float*   pooled = (float*)base;   base += (size_t)n_graphs * 32 * 4;   // zeroed
    int*     cnt    = (int*)base;     base += (size_t)NCHUNK * NB * 4;     // 3.2 MB
    int*     offTT  = (int*)base;     base += (size_t)NCHUNK * NB * 4;     // 3.2 MB
    int*     tot    = (int*)base;     base += (size_t)NB * 4;
    int*     base_  = (int*)base;     base += (size_t)(NB + 1) * 4;
    float*   Wfull  = (float*)base;   base += 2048 * 4;
    float*   hWbias = (float*)base;   base += 32 * 4;
    uint8_t* ewc    = (uint8_t*)base; base += align_up((size_t)n_edges, 64);
    int*     csrB   = (int*)base;     base += (size_t)n_edges * 4;         // 12 MB
    base = (char*)align_up((size_t)base, 64);
    __half*  hWs    = (__half*)base;  base += (size_t)n_nodes * 32 * 2;    // 6.4 MB

    hipMemsetAsync(pooled, 0, (size_t)n_graphs * 32 * 4, stream);

    kA1<<<NCHUNK + 128, BLK, 0, stream>>>(col, cnt, n_edges, NB,
                                          km, um, om, s0, s1, s2, ewc);
    kB2<<<NGB, BLK, 0, stream>>>(cnt, offTT, tot, NB);
    kBase3<<<9, BLK, 0, stream>>>(tot, base_, NB, emb_W, emb_b, gcn_W, Wfull, hWbias);
    kC_scatter<<<NCHUNK, BLK, 0, stream>>>(row, col, ewc, base_, offTT, csrB,
                                           n_edges, NB);
    k4f_gemm<<<NB, BLK, 0, stream>>>(x, Wfull, hWbias, base_, csrB, mw, hWs, n_nodes);
    kD_gather<<<NB, BLK, 0, stream>>>(base_, csrB, (const __half2*)hWs, mw,
                                      gcn_b, batch, pooled, n_nodes);
    k7_head<<<1, BLK, 0, stream>>>(pooled, fc1_W, fc1_b, out_W, out_b, (float*)d_out, n_graphs);
}